// Round 1
// baseline (1192.770 us; speedup 1.0000x reference)
//
#include <hip/hip_runtime.h>
#include <stdint.h>

// ---------------------------------------------------------------------------
// SelfAttention (pre-norm, shared-V) on MI355X / gfx950
// out  = (softmax((xn Wq^T)(xn Wk^T)^T / 16) @ xn) @ Wv^T + xn,  probs also output
// All GEMMs via v_mfma_f32_16x16x32_bf16, staging via global_load_lds width=16.
// Verified fragment maps (learn_hip m89/m120):
//   A-frag: A[m = lane&15][k = (lane>>4)*8 + j]
//   B-frag: B[n = lane&15][k = (lane>>4)*8 + j]   (BT form: both row-major, K inner)
//   C/D   : D[m = (lane>>4)*4 + r][n = lane&15]
// ---------------------------------------------------------------------------

typedef __bf16 bh8 __attribute__((ext_vector_type(8)));
typedef float f32x4 __attribute__((ext_vector_type(4)));

#define MFMA16(a, b, c) __builtin_amdgcn_mfma_f32_16x16x32_bf16((a), (b), (c), 0, 0, 0)

__device__ __forceinline__ uint16_t f2b(float f) {  // fp32 -> bf16 RNE
  uint32_t u = __float_as_uint(f);
  u += 0x7FFFu + ((u >> 16) & 1u);
  return (uint16_t)(u >> 16);
}
__device__ __forceinline__ uint32_t pack2(float a, float b) {
  return (uint32_t)f2b(a) | ((uint32_t)f2b(b) << 16);
}
// async global->LDS, 16B per lane; lds base must be wave-uniform (HW adds lane*16)
__device__ __forceinline__ void async16(const uint16_t* g, uint16_t* l) {
  __builtin_amdgcn_global_load_lds((__attribute__((address_space(1))) const uint32_t*)g,
                                   (__attribute__((address_space(3))) uint32_t*)l, 16, 0, 0);
}

// ---------------- LayerNorm: x -> xn fp32 (residual) + xn bf16 --------------
__global__ __launch_bounds__(256) void ln_kernel(
    const float* __restrict__ x, const float* __restrict__ gamma,
    const float* __restrict__ beta, float* __restrict__ xnf, uint16_t* __restrict__ xnb) {
  const int wave = threadIdx.x >> 6, lane = threadIdx.x & 63;
  const size_t row = (size_t)blockIdx.x * 4 + wave;  // one wave per 256-elem row
  const float4 v = *(const float4*)(x + row * 256 + lane * 4);
  float s = v.x + v.y + v.z + v.w;
  float ss = v.x * v.x + v.y * v.y + v.z * v.z + v.w * v.w;
#pragma unroll
  for (int d = 32; d; d >>= 1) { s += __shfl_xor(s, d); ss += __shfl_xor(ss, d); }
  const float mu = s * (1.0f / 256.0f);
  const float inv = rsqrtf(ss * (1.0f / 256.0f) - mu * mu + 1e-5f);
  const float4 g = *(const float4*)(gamma + lane * 4);
  const float4 be = *(const float4*)(beta + lane * 4);
  float4 o;
  o.x = (v.x - mu) * inv * g.x + be.x;
  o.y = (v.y - mu) * inv * g.y + be.y;
  o.z = (v.z - mu) * inv * g.z + be.z;
  o.w = (v.w - mu) * inv * g.w + be.w;
  *(float4*)(xnf + row * 256 + lane * 4) = o;
  ushort4 ob;
  ob.x = f2b(o.x); ob.y = f2b(o.y); ob.z = f2b(o.z); ob.w = f2b(o.w);
  *(ushort4*)(xnb + row * 256 + lane * 4) = ob;
}

// ---------------- fp32 -> bf16 weight conversion ----------------------------
__global__ __launch_bounds__(256) void cvt_kernel(const float* __restrict__ in,
                                                  uint16_t* __restrict__ out2, int n) {
  int i = blockIdx.x * 256 + threadIdx.x;
  if (i < n) out2[i] = f2b(in[i]);
}

// ---------------- xn (b,1024,256) -> xnT (b,256,1024) bf16 ------------------
__global__ __launch_bounds__(256) void transpose_xn(
    const uint16_t* __restrict__ xnb, uint16_t* __restrict__ xnT) {
  const int b = blockIdx.z, it = blockIdx.y, dt = blockIdx.x;  // 64x64 tiles
  __shared__ uint16_t tile[64][65];
  const int t = threadIdx.x;
  const int r = t >> 2, c0 = (t & 3) * 16;
  const uint16_t* src = xnb + ((size_t)b * 1024 + it * 64) * 256 + dt * 64;
#pragma unroll
  for (int i = 0; i < 16; ++i) tile[r][c0 + i] = src[(size_t)r * 256 + c0 + i];
  __syncthreads();
  uint16_t* dst = xnT + ((size_t)b * 256 + dt * 64) * 1024 + it * 64;
#pragma unroll
  for (int i = 0; i < 16; ++i) dst[(size_t)r * 1024 + c0 + i] = tile[c0 + i][r];
}

// ---------------- BT GEMM: C(MxN) = A(MxK) @ B(NxK)^T, 128x128 tile ---------
// RES=false: C bf16.  RES=true: C fp32 = acc + resid (residual add).
template <int K, int N, bool RES>
__global__ __launch_bounds__(256) void gemm_bt(
    const uint16_t* __restrict__ A, const uint16_t* __restrict__ B,
    void* __restrict__ Cv, const float* __restrict__ resid) {
  const int m0 = blockIdx.x * 128, n0 = blockIdx.y * 128;
  const int t = threadIdx.x;
  const int lane = t & 63, wave = t >> 6;
  const int l15 = lane & 15, quad = lane >> 4;
  const int wm = (wave >> 1) * 64, wn = (wave & 1) * 64;  // 2x2 waves of 64x64

  __shared__ uint16_t As[128 * 32];
  __shared__ uint16_t Bs[128 * 32];

  f32x4 acc[4][4];
#pragma unroll
  for (int mi = 0; mi < 4; ++mi)
#pragma unroll
    for (int ni = 0; ni < 4; ++ni)
#pragma unroll
      for (int r = 0; r < 4; ++r) acc[mi][ni][r] = 0.0f;

  for (int k0 = 0; k0 < K; k0 += 32) {
#pragma unroll
    for (int j = 0; j < 2; ++j) {
      int cc = j * 256 + t;
      int row = cc >> 2, ko = (cc & 3) << 3;
      async16(A + (size_t)(m0 + row) * K + k0 + ko, &As[(j * 256 + (t & ~63)) * 8]);
      async16(B + (size_t)(n0 + row) * K + k0 + ko, &Bs[(j * 256 + (t & ~63)) * 8]);
    }
    __syncthreads();
    bh8 afr[4], bfr[4];
#pragma unroll
    for (int mi = 0; mi < 4; ++mi) afr[mi] = *(const bh8*)&As[(wm + mi * 16 + l15) * 32 + quad * 8];
#pragma unroll
    for (int ni = 0; ni < 4; ++ni) bfr[ni] = *(const bh8*)&Bs[(wn + ni * 16 + l15) * 32 + quad * 8];
#pragma unroll
    for (int mi = 0; mi < 4; ++mi)
#pragma unroll
      for (int ni = 0; ni < 4; ++ni) acc[mi][ni] = MFMA16(afr[mi], bfr[ni], acc[mi][ni]);
    __syncthreads();
  }
#pragma unroll
  for (int mi = 0; mi < 4; ++mi)
#pragma unroll
    for (int ni = 0; ni < 4; ++ni)
#pragma unroll
      for (int r = 0; r < 4; ++r) {
        size_t m = (size_t)(m0 + wm + mi * 16 + quad * 4 + r);
        size_t n = (size_t)(n0 + wn + ni * 16 + l15);
        if constexpr (RES) {
          ((float*)Cv)[m * N + n] = acc[mi][ni][r] + resid[m * N + n];
        } else {
          ((uint16_t*)Cv)[m * N + n] = f2b(acc[mi][ni][r]);
        }
      }
}

// ---------------- fused scores + softmax ------------------------------------
// block = 32 Q-rows x full 1024 K-cols for one (b,h); 4 waves split columns.
// K-matrix staged in two 512-row LDS halves (keeps LDS at ~35 KB).
__global__ __launch_bounds__(256) void attn_scores(
    const uint16_t* __restrict__ Qp, const uint16_t* __restrict__ Kp,
    float* __restrict__ probs) {
  const int rb = blockIdx.x;  // 32 row-blocks
  const int z = blockIdx.y;   // b*8 + h
  const int b = z >> 3, h = z & 7;
  const int t = threadIdx.x;
  const int lane = t & 63, wave = t >> 6;
  const int l15 = lane & 15, quad = lane >> 4;
  const int m0 = rb * 32;

  const uint16_t* Qb = Qp + (size_t)b * 1024 * 2048 + (size_t)h * 256;
  const uint16_t* Kb = Kp + (size_t)b * 1024 * 2048 + (size_t)h * 256;

  __shared__ uint16_t As[32 * 32];    // 2 KB
  __shared__ uint16_t Bs[512 * 32];   // 32 KB
  __shared__ float redmax[32][4];
  __shared__ float redsum[32][4];

  f32x4 acc[2][16];
#pragma unroll
  for (int mi = 0; mi < 2; ++mi)
#pragma unroll
    for (int ni = 0; ni < 16; ++ni)
#pragma unroll
      for (int r = 0; r < 4; ++r) acc[mi][ni][r] = 0.0f;

  bh8 af[2];
  for (int k0 = 0; k0 < 256; k0 += 32) {
#pragma unroll
    for (int half = 0; half < 2; ++half) {
      if (half == 0 && t < 128) {  // A tile 32x32 (waves 0,1 only; wave-uniform branch)
        int row = t >> 2, ko = (t & 3) << 3;
        async16(Qb + (size_t)(m0 + row) * 2048 + k0 + ko, &As[(t & ~63) * 8]);
      }
#pragma unroll
      for (int j = 0; j < 8; ++j) {  // B half-tile 512x32
        int cc = j * 256 + t;
        int row = half * 512 + (cc >> 2), ko = (cc & 3) << 3;
        async16(Kb + (size_t)row * 2048 + k0 + ko, &Bs[(j * 256 + (t & ~63)) * 8]);
      }
      __syncthreads();
      if (half == 0) {
        af[0] = *(const bh8*)&As[l15 * 32 + quad * 8];
        af[1] = *(const bh8*)&As[(16 + l15) * 32 + quad * 8];
      }
#pragma unroll
      for (int ni = 0; ni < 8; ++ni) {
        bh8 bf = *(const bh8*)&Bs[(wave * 128 + ni * 16 + l15) * 32 + quad * 8];
        acc[0][half * 8 + ni] = MFMA16(af[0], bf, acc[0][half * 8 + ni]);
        acc[1][half * 8 + ni] = MFMA16(af[1], bf, acc[1][half * 8 + ni]);
      }
      __syncthreads();
    }
  }

  // softmax over each row's 1024 raw scores (scale 1/16 folded into exp2)
  const float sc = 0.0625f * 1.44269504f;
  float rowm[2][4];
#pragma unroll
  for (int mi = 0; mi < 2; ++mi)
#pragma unroll
    for (int r = 0; r < 4; ++r) {
      float m = acc[mi][0][r];
#pragma unroll
      for (int ni = 1; ni < 16; ++ni) m = fmaxf(m, acc[mi][ni][r]);
#pragma unroll
      for (int d = 1; d < 16; d <<= 1) m = fmaxf(m, __shfl_xor(m, d));
      rowm[mi][r] = m;
    }
  if (l15 == 0) {
#pragma unroll
    for (int mi = 0; mi < 2; ++mi)
#pragma unroll
      for (int r = 0; r < 4; ++r) redmax[mi * 16 + quad * 4 + r][wave] = rowm[mi][r];
  }
  __syncthreads();
#pragma unroll
  for (int mi = 0; mi < 2; ++mi)
#pragma unroll
    for (int r = 0; r < 4; ++r) {
      int row = mi * 16 + quad * 4 + r;
      rowm[mi][r] = fmaxf(fmaxf(redmax[row][0], redmax[row][1]),
                          fmaxf(redmax[row][2], redmax[row][3]));
    }
  float rsum[2][4];
#pragma unroll
  for (int mi = 0; mi < 2; ++mi)
#pragma unroll
    for (int r = 0; r < 4; ++r) rsum[mi][r] = 0.0f;
#pragma unroll
  for (int mi = 0; mi < 2; ++mi)
#pragma unroll
    for (int ni = 0; ni < 16; ++ni)
#pragma unroll
      for (int r = 0; r < 4; ++r) {
        float e = exp2f((acc[mi][ni][r] - rowm[mi][r]) * sc);
        acc[mi][ni][r] = e;
        rsum[mi][r] += e;
      }
#pragma unroll
  for (int mi = 0; mi < 2; ++mi)
#pragma unroll
    for (int r = 0; r < 4; ++r) {
#pragma unroll
      for (int d = 1; d < 16; d <<= 1) rsum[mi][r] += __shfl_xor(rsum[mi][r], d);
    }
  if (l15 == 0) {
#pragma unroll
    for (int mi = 0; mi < 2; ++mi)
#pragma unroll
      for (int r = 0; r < 4; ++r) redsum[mi * 16 + quad * 4 + r][wave] = rsum[mi][r];
  }
  __syncthreads();
  float rinv[2][4];
#pragma unroll
  for (int mi = 0; mi < 2; ++mi)
#pragma unroll
    for (int r = 0; r < 4; ++r) {
      int row = mi * 16 + quad * 4 + r;
      rinv[mi][r] = 1.0f / (redsum[row][0] + redsum[row][1] + redsum[row][2] + redsum[row][3]);
    }
  float* P = probs + (size_t)z * 1024 * 1024 + (size_t)m0 * 1024;
#pragma unroll
  for (int mi = 0; mi < 2; ++mi)
#pragma unroll
    for (int ni = 0; ni < 16; ++ni)
#pragma unroll
      for (int r = 0; r < 4; ++r) {
        int row = mi * 16 + quad * 4 + r;
        int col = (ni >> 3) * 512 + wave * 128 + (ni & 7) * 16 + l15;
        P[(size_t)row * 1024 + col] = acc[mi][ni][r] * rinv[mi][r];
      }
}

// ---------------- context GEMM: ctx(b,h) = probs(b,h) @ xn(b) ---------------
// A = probs fp32 (converted to bf16 during staging), B = xnT bf16 (BT form).
// BM=128, BN=256 (full width -> probs read exactly once), 512 threads.
__global__ __launch_bounds__(512) void gemm_ctx(
    const float* __restrict__ P, const uint16_t* __restrict__ XT,
    uint16_t* __restrict__ ctx) {
  const int mt = blockIdx.x;  // 8 m-tiles
  const int z = blockIdx.z;   // 128 (b,h)
  const int b = z >> 3, h = z & 7;
  const int t = threadIdx.x;
  const int lane = t & 63, wave = t >> 6;
  const int l15 = lane & 15, quad = lane >> 4;
  const int wm = (wave >> 2) * 64, wn = (wave & 3) * 64;  // 2x4 waves of 64x64
  const int m0 = mt * 128;
  const float* Ab = P + (size_t)z * 1024 * 1024;
  const uint16_t* Bb = XT + (size_t)b * 256 * 1024;

  __shared__ uint16_t As[128 * 32];  // 8 KB
  __shared__ uint16_t Bs[256 * 32];  // 16 KB

  f32x4 acc[4][4];
#pragma unroll
  for (int mi = 0; mi < 4; ++mi)
#pragma unroll
    for (int ni = 0; ni < 4; ++ni)
#pragma unroll
      for (int r = 0; r < 4; ++r) acc[mi][ni][r] = 0.0f;

  const int arow = t >> 2, aco = (t & 3) * 8;
  for (int k0 = 0; k0 < 1024; k0 += 32) {
    {  // A stage: 8 floats/thread, convert to bf16, one 16B LDS store
      const float* g = Ab + (size_t)(m0 + arow) * 1024 + k0 + aco;
      float4 f0 = *(const float4*)g;
      float4 f1 = *(const float4*)(g + 4);
      uint4 pk;
      pk.x = pack2(f0.x, f0.y); pk.y = pack2(f0.z, f0.w);
      pk.z = pack2(f1.x, f1.y); pk.w = pack2(f1.z, f1.w);
      *(uint4*)&As[arow * 32 + aco] = pk;
    }
#pragma unroll
    for (int j = 0; j < 2; ++j) {  // B stage: 256x32 bf16 async
      int cc = j * 512 + t;
      int row = cc >> 2, ko = (cc & 3) << 3;
      async16(Bb + (size_t)row * 1024 + k0 + ko, &Bs[(j * 512 + (t & ~63)) * 8]);
    }
    __syncthreads();
    bh8 afr[4], bfr[4];
#pragma unroll
    for (int mi = 0; mi < 4; ++mi) afr[mi] = *(const bh8*)&As[(wm + mi * 16 + l15) * 32 + quad * 8];
#pragma unroll
    for (int ni = 0; ni < 4; ++ni) bfr[ni] = *(const bh8*)&Bs[(wn + ni * 16 + l15) * 32 + quad * 8];
#pragma unroll
    for (int mi = 0; mi < 4; ++mi)
#pragma unroll
      for (int ni = 0; ni < 4; ++ni) acc[mi][ni] = MFMA16(afr[mi], bfr[ni], acc[mi][ni]);
    __syncthreads();
  }
  const size_t growbase = (size_t)b * 1024 + m0 + wm;
#pragma unroll
  for (int mi = 0; mi < 4; ++mi)
#pragma unroll
    for (int ni = 0; ni < 4; ++ni)
#pragma unroll
      for (int r = 0; r < 4; ++r) {
        size_t grow = growbase + mi * 16 + quad * 4 + r;
        int col = h * 256 + wn + ni * 16 + l15;
        ctx[grow * 2048 + col] = f2b(acc[mi][ni][r]);
      }
}

// ---------------------------------------------------------------------------
extern "C" void kernel_launch(void* const* d_in, const int* in_sizes, int n_in,
                              void* d_out, int out_size, void* d_ws, size_t ws_size,
                              hipStream_t stream) {
  const float* x = (const float*)d_in[0];
  const float* Wq = (const float*)d_in[1];
  const float* Wk = (const float*)d_in[2];
  const float* Wv = (const float*)d_in[3];
  const float* gamma = (const float*)d_in[4];
  const float* beta = (const float*)d_in[5];
  float* out = (float*)d_out;
  float* probs = out + (size_t)16 * 1024 * 256;  // outputs concatenated: out, probs

  // workspace layout (bytes); total ~227 MB
  char* ws = (char*)d_ws;
  float* xnf = (float*)(ws + 0);                      // 16 MB fp32 xn (residual)
  uint16_t* xnb = (uint16_t*)(ws + 16777216);         // 8 MB  bf16 xn
  uint16_t* xnT = (uint16_t*)(ws + 25165824);         // 8 MB  bf16 xn^T per batch
  uint16_t* wqb = (uint16_t*)(ws + 33554432);         // 1 MB
  uint16_t* wkb = (uint16_t*)(ws + 34603008);         // 1 MB
  uint16_t* wvb = (uint16_t*)(ws + 35651584);         // 1 MB
  uint16_t* Qp = (uint16_t*)(ws + 36700160);          // 64 MB (16384 x 2048 bf16)
  uint16_t* Kp = (uint16_t*)(ws + 103809024);         // 64 MB
  uint16_t* ctx = (uint16_t*)(ws + 170917888);        // 64 MB

  ln_kernel<<<4096, 256, 0, stream>>>(x, gamma, beta, xnf, xnb);
  cvt_kernel<<<2048, 256, 0, stream>>>(Wq, wqb, 2048 * 256);
  cvt_kernel<<<2048, 256, 0, stream>>>(Wk, wkb, 2048 * 256);
  cvt_kernel<<<2048, 256, 0, stream>>>(Wv, wvb, 256 * 2048);
  transpose_xn<<<dim3(4, 16, 16), 256, 0, stream>>>(xnb, xnT);
  gemm_bt<256, 2048, false><<<dim3(128, 16), 256, 0, stream>>>(xnb, wqb, (void*)Qp, nullptr);
  gemm_bt<256, 2048, false><<<dim3(128, 16), 256, 0, stream>>>(xnb, wkb, (void*)Kp, nullptr);
  attn_scores<<<dim3(32, 128), 256, 0, stream>>>(Qp, Kp, probs);
  gemm_ctx<<<dim3(8, 1, 128), 512, 0, stream>>>(probs, xnT, ctx);
  gemm_bt<2048, 256, true><<<dim3(128, 2), 256, 0, stream>>>(ctx, wvb, (void*)out, xnf);
}